// Round 5
// baseline (191.652 us; speedup 1.0000x reference)
//
#include <hip/hip_runtime.h>

#define TOPK 32

typedef float vfloat4 __attribute__((ext_vector_type(4)));

// ---------------------------------------------------------------------------
// K1: streaming dot. One wave per row (b,p):
//   d2[b,p] = dot(base[b,p,:], W[b,:])
// Sequential read of ALL of base (256 MB == L3 size) -> leaves base resident
// in L3 for K3's re-read. Perfectly coalesced, no atomics.
// ---------------------------------------------------------------------------
__global__ void dot_kernel(const float* __restrict__ base,
                           const float* __restrict__ bw,
                           float* __restrict__ d2,
                           int S, int H) {
    int wid  = (blockIdx.x * blockDim.x + threadIdx.x) >> 6;  // row = b*S + p
    int lane = threadIdx.x & 63;
    int b = wid / S;

    const float4* row = (const float4*)(base + (size_t)wid * H);
    const float4* w4  = (const float4*)(bw + (size_t)b * H);
    int n4 = H >> 2;                      // 512

    float acc = 0.f;
    #pragma unroll 8
    for (int i = lane; i < n4; i += 64) {
        float4 v = row[i];
        float4 w = w4[i];
        acc += v.x * w.x + v.y * w.y + v.z * w.z + v.w * w.w;
    }
    #pragma unroll
    for (int off = 32; off > 0; off >>= 1)
        acc += __shfl_down(acc, off, 64);

    if (lane == 0) d2[wid] = acc;
}

// ---------------------------------------------------------------------------
// K2: one block per batch. Gathers d2 -> detect in LDS, counts via LDS
// atomics, then top-32 by a SINGLE wave (barrier-free): 32 iterations of
// argmax, ties -> lower index (exact lax.top_k). Writes detect/nontopk/counts.
// ---------------------------------------------------------------------------
__global__ void topk_kernel(const float* __restrict__ d2,
                            const int* __restrict__ pos,
                            float* __restrict__ detect,
                            float* __restrict__ nontopk,
                            int* __restrict__ counts,
                            float* __restrict__ meanv,
                            int S) {
    extern __shared__ float smem[];
    float* dvals = smem;                  // S floats: d2 for this batch
    float* vals  = smem + S;              // S floats: detect (mutated by topk)
    int*   cnt   = (int*)(smem + 2 * S);  // S ints

    int b = blockIdx.x;
    int t = threadIdx.x;
    int T = blockDim.x;                   // 256

    for (int i = t; i < S; i += T) {
        dvals[i] = d2[(size_t)b * S + i];
        cnt[i] = 0;
    }
    __syncthreads();
    for (int i = t; i < S; i += T) {
        int p = pos[(size_t)b * S + i];
        float v = fmaxf(dvals[p], 0.f);
        vals[i] = v;
        detect[(size_t)b * S + i] = v;
        atomicAdd(&cnt[p], 1);
    }
    __syncthreads();

    if (t < 64) {                         // wave 0 only: no barriers needed
        int lane = t;
        float sum = 0.f;
        for (int it = 0; it < TOPK; ++it) {
            float lv = -INFINITY;
            int   li = 0x7fffffff;
            for (int c = lane * 4; c < S; c += 256) {
                float4 v = *(const float4*)&vals[c];
                if (v.x > lv) { lv = v.x; li = c; }
                if (v.y > lv) { lv = v.y; li = c + 1; }
                if (v.z > lv) { lv = v.z; li = c + 2; }
                if (v.w > lv) { lv = v.w; li = c + 3; }
            }
            #pragma unroll
            for (int off = 32; off > 0; off >>= 1) {
                float ov = __shfl_down(lv, off, 64);
                int   oi = __shfl_down(li, off, 64);
                if (ov > lv || (ov == lv && oi < li)) { lv = ov; li = oi; }
            }
            lv = __shfl(lv, 0, 64);
            li = __shfl(li, 0, 64);
            sum += lv;
            if (lane == 0) vals[li] = -INFINITY;  // wave-synchronous LDS update
        }
        if (lane == 0) meanv[b] = sum / (float)TOPK;
    }
    __syncthreads();

    for (int i = t; i < S; i += T) {
        float v = vals[i];
        nontopk[(size_t)b * S + i] = (v == -INFINITY) ? 0.f : v;
        counts[(size_t)b * S + i] = cnt[i];
    }
}

// ---------------------------------------------------------------------------
// K3: 4 consecutive rows per block:
//   mixed[b,p,:] = base[b,p,:] + counts[b,p]*mean[b]*W[b,:]
// base read should be L3-resident (primed by K1); non-temporal stores keep
// the 256 MB of mixed writes from evicting base.
// ---------------------------------------------------------------------------
__global__ void mix_kernel(const float* __restrict__ base,
                           const float* __restrict__ bw,
                           const int* __restrict__ counts,
                           const float* __restrict__ meanv,
                           float* __restrict__ mixed,
                           int S, int H) {
    int r0 = blockIdx.x << 2;
    int b  = r0 / S;
    const float4* w4 = (const float4*)(bw + (size_t)b * H);
    float mb = meanv[b];
    int n4 = H >> 2;                      // 512

    for (int r = r0; r < r0 + 4; ++r) {
        float scale = (float)counts[r] * mb;
        const float4* b4 = (const float4*)(base + (size_t)r * H);
        vfloat4*      o4 = (vfloat4*)(mixed + (size_t)r * H);
        #pragma unroll 2
        for (int i = threadIdx.x; i < n4; i += blockDim.x) {
            float4 v = b4[i];
            float4 w = w4[i];
            vfloat4 o;
            o.x = v.x + scale * w.x;
            o.y = v.y + scale * w.y;
            o.z = v.z + scale * w.z;
            o.w = v.w + scale * w.w;
            __builtin_nontemporal_store(o, &o4[i]);
        }
    }
}

// ---------------------------------------------------------------------------
extern "C" void kernel_launch(void* const* d_in, const int* in_sizes, int n_in,
                              void* d_out, int out_size, void* d_ws, size_t ws_size,
                              hipStream_t stream) {
    const float* base = (const float*)d_in[0];
    const int*   pos  = (const int*)d_in[1];
    const float* bw   = (const float*)d_in[2];

    long n0 = in_sizes[0];               // B*S*H
    long n1 = in_sizes[1];               // B*S
    long n2 = in_sizes[2];               // B*H
    int H = (int)(n0 / n1);
    int B = (int)(n2 / H);
    int S = (int)(n1 / B);

    float* out_mixed   = (float*)d_out;
    float* out_detect  = out_mixed + (size_t)B * S * H;
    float* out_nontopk = out_detect + (size_t)B * S;

    int*   counts = (int*)d_ws;
    float* d2     = (float*)((char*)d_ws + (size_t)B * S * sizeof(int));
    float* meanv  = (float*)((char*)d_ws + 2 * (size_t)B * S * sizeof(int));

    int nrows = B * S;
    dot_kernel<<<nrows / 4, 256, 0, stream>>>(base, bw, d2, S, H);
    topk_kernel<<<B, 256, 3 * (size_t)S * sizeof(float), stream>>>(
        d2, pos, out_detect, out_nontopk, counts, meanv, S);
    mix_kernel<<<nrows / 4, 256, 0, stream>>>(base, bw, counts, meanv, out_mixed, S, H);
}

// Round 7
// 177.616 us; speedup vs baseline: 1.0790x; 1.0790x over previous
//
#include <hip/hip_runtime.h>

#define TOPK 32

typedef float vfloat4 __attribute__((ext_vector_type(4)));

// ---------------------------------------------------------------------------
// K0: per-batch histogram of pos -> counts.  B blocks, LDS atomics. ~3us.
// ---------------------------------------------------------------------------
__global__ void hist_kernel(const int* __restrict__ pos,
                            int* __restrict__ counts,
                            int S) {
    extern __shared__ int cnt[];          // S ints
    int b = blockIdx.x;
    int t = threadIdx.x;
    for (int i = t; i < S; i += 256) cnt[i] = 0;
    __syncthreads();
    for (int i = t; i < S; i += 256)
        atomicAdd(&cnt[pos[(size_t)b * S + i]], 1);
    __syncthreads();
    for (int i = t; i < S; i += 256)
        counts[(size_t)b * S + i] = cnt[i];
}

// ---------------------------------------------------------------------------
// K1: one wave per row (b,p); dots ONLY for referenced rows (count>0, ~63%).
//   d2[row] = dot(base[row,:], W[b,:])
// Skipping unreferenced rows saves ~94MB of HBM reads. 8KB-row-granular
// reads remain fully coalesced.
// ---------------------------------------------------------------------------
__global__ void dot_kernel(const float* __restrict__ base,
                           const float* __restrict__ bw,
                           const int* __restrict__ counts,
                           float* __restrict__ d2,
                           int S, int H) {
    int wid  = (blockIdx.x * blockDim.x + threadIdx.x) >> 6;  // row = b*S + p
    int lane = threadIdx.x & 63;
    if (counts[wid] == 0) return;
    int b = wid / S;

    const float4* row = (const float4*)(base + (size_t)wid * H);
    const float4* w4  = (const float4*)(bw + (size_t)b * H);
    int n4 = H >> 2;                      // 512

    float acc = 0.f;
    #pragma unroll 8
    for (int i = lane; i < n4; i += 64) {
        float4 v = row[i];
        float4 w = w4[i];
        acc += v.x * w.x + v.y * w.y + v.z * w.z + v.w * w.w;
    }
    #pragma unroll
    for (int off = 32; off > 0; off >>= 1)
        acc += __shfl_down(acc, off, 64);

    if (lane == 0) d2[wid] = acc;
}

// ---------------------------------------------------------------------------
// K2: one block per batch. Gather d2 -> detect (LDS), then top-32 by a
// SINGLE wave (barrier-free): 32x argmax, ties -> lower index (lax.top_k).
// ---------------------------------------------------------------------------
__global__ void topk_kernel(const float* __restrict__ d2,
                            const int* __restrict__ pos,
                            float* __restrict__ detect,
                            float* __restrict__ nontopk,
                            float* __restrict__ meanv,
                            int S) {
    extern __shared__ float smem[];
    float* dvals = smem;                  // S floats: d2 for this batch
    float* vals  = smem + S;              // S floats: detect (mutated)

    int b = blockIdx.x;
    int t = threadIdx.x;

    for (int i = t; i < S; i += 256)
        dvals[i] = d2[(size_t)b * S + i];
    __syncthreads();
    for (int i = t; i < S; i += 256) {
        float v = fmaxf(dvals[pos[(size_t)b * S + i]], 0.f);
        vals[i] = v;
        detect[(size_t)b * S + i] = v;
    }
    __syncthreads();

    if (t < 64) {                         // wave 0 only: no barriers needed
        int lane = t;
        float sum = 0.f;
        for (int it = 0; it < TOPK; ++it) {
            float lv = -INFINITY;
            int   li = 0x7fffffff;
            for (int c = lane * 4; c < S; c += 256) {
                float4 v = *(const float4*)&vals[c];
                if (v.x > lv) { lv = v.x; li = c; }
                if (v.y > lv) { lv = v.y; li = c + 1; }
                if (v.z > lv) { lv = v.z; li = c + 2; }
                if (v.w > lv) { lv = v.w; li = c + 3; }
            }
            #pragma unroll
            for (int off = 32; off > 0; off >>= 1) {
                float ov = __shfl_down(lv, off, 64);
                int   oi = __shfl_down(li, off, 64);
                if (ov > lv || (ov == lv && oi < li)) { lv = ov; li = oi; }
            }
            lv = __shfl(lv, 0, 64);
            li = __shfl(li, 0, 64);
            sum += lv;
            if (lane == 0) vals[li] = -INFINITY;  // wave-synchronous LDS update
        }
        if (lane == 0) meanv[b] = sum / (float)TOPK;
    }
    __syncthreads();

    for (int i = t; i < S; i += 256) {
        float v = vals[i];
        nontopk[(size_t)b * S + i] = (v == -INFINITY) ? 0.f : v;
    }
}

// ---------------------------------------------------------------------------
// K3: 4 consecutive rows per block:
//   mixed[b,p,:] = base[b,p,:] + counts[b,p]*mean[b]*W[b,:]
// Non-temporal stores for the streamed output.
// ---------------------------------------------------------------------------
__global__ void mix_kernel(const float* __restrict__ base,
                           const float* __restrict__ bw,
                           const int* __restrict__ counts,
                           const float* __restrict__ meanv,
                           float* __restrict__ mixed,
                           int S, int H) {
    int r0 = blockIdx.x << 2;
    int b  = r0 / S;
    const float4* w4 = (const float4*)(bw + (size_t)b * H);
    float mb = meanv[b];
    int n4 = H >> 2;                      // 512

    for (int r = r0; r < r0 + 4; ++r) {
        float scale = (float)counts[r] * mb;
        const float4* b4 = (const float4*)(base + (size_t)r * H);
        vfloat4*      o4 = (vfloat4*)(mixed + (size_t)r * H);
        #pragma unroll 2
        for (int i = threadIdx.x; i < n4; i += blockDim.x) {
            float4 v = b4[i];
            float4 w = w4[i];
            vfloat4 o;
            o.x = v.x + scale * w.x;
            o.y = v.y + scale * w.y;
            o.z = v.z + scale * w.z;
            o.w = v.w + scale * w.w;
            __builtin_nontemporal_store(o, &o4[i]);
        }
    }
}

// ---------------------------------------------------------------------------
extern "C" void kernel_launch(void* const* d_in, const int* in_sizes, int n_in,
                              void* d_out, int out_size, void* d_ws, size_t ws_size,
                              hipStream_t stream) {
    const float* base = (const float*)d_in[0];
    const int*   pos  = (const int*)d_in[1];
    const float* bw   = (const float*)d_in[2];

    long n0 = in_sizes[0];               // B*S*H
    long n1 = in_sizes[1];               // B*S
    long n2 = in_sizes[2];               // B*H
    int H = (int)(n0 / n1);
    int B = (int)(n2 / H);
    int S = (int)(n1 / B);

    float* out_mixed   = (float*)d_out;
    float* out_detect  = out_mixed + (size_t)B * S * H;
    float* out_nontopk = out_detect + (size_t)B * S;

    int*   counts = (int*)d_ws;
    float* d2     = (float*)((char*)d_ws + (size_t)B * S * sizeof(int));
    float* meanv  = (float*)((char*)d_ws + 2 * (size_t)B * S * sizeof(int));

    int nrows = B * S;
    hist_kernel<<<B, 256, (size_t)S * sizeof(int), stream>>>(pos, counts, S);
    dot_kernel<<<nrows / 4, 256, 0, stream>>>(base, bw, counts, d2, S, H);
    topk_kernel<<<B, 256, 2 * (size_t)S * sizeof(float), stream>>>(
        d2, pos, out_detect, out_nontopk, meanv, S);
    mix_kernel<<<nrows / 4, 256, 0, stream>>>(base, bw, counts, meanv, out_mixed, S, H);
}